// Round 3
// baseline (281464.893 us; speedup 1.0000x reference)
//
#include <hip/hip_runtime.h>
#include <hip/hip_bf16.h>

#define NWG 32         // active workers (one XCD)
#define NWGL 256       // launched WGs (1 per CU)
#define TSEQ 512
#define JW 16          // h-columns per WG
#define HH 512
#define II 1024
#define GSTRIDE 1280   // padded row stride of G (floats/bf16 elements)
#define CHK 12         // 16B chunks per record: 36 floats = h[16] + c[16] + wp[4]
// payload map: [0..15]=h, [16..31]=c, [32..35]=wp logits (cols ci*32+w)

// workspace byte offsets
#define OFF_RECF   4096u                       // fast (sc0, XCD-L2) records: 2*32*12*16B
#define OFF_RECS   20480u                      // slow (sc1, IC) records
#define OFF_WSTACK (1u<<20)                    // 1025*1280 f32 ~ 5.25 MB
#define OFF_G      (16u<<20)                   // N*1280 bf16 ~ 84 MB

typedef float fx4 __attribute__((ext_vector_type(4)));

__device__ __forceinline__ float bf2f(__hip_bfloat16 x){ return __bfloat162float(x); }
__device__ __forceinline__ unsigned f2u(float x){ return __builtin_bit_cast(unsigned, x); }
__device__ __forceinline__ float u2f(unsigned x){ return __builtin_bit_cast(float, x); }

// sc1: device-coherent at Infinity Cache (proven path)
__device__ __forceinline__ void ld_chunk_sc1(const fx4* p, fx4& a){
  asm volatile("global_load_dwordx4 %0, %1, off sc1\n\t"
               "s_waitcnt vmcnt(0)"
               : "=&v"(a) : "v"(p) : "memory");
}
__device__ __forceinline__ void st_chunk_sc1(fx4* p, fx4 v){
  asm volatile("global_store_dwordx4 %0, %1, off sc1" :: "v"(p), "v"(v) : "memory");
}
// sc0: L1-bypass; within one XCD all CUs share L2 -> low-latency coherence (fast path)
__device__ __forceinline__ void ld_chunk_sc0(const fx4* p, fx4& a){
  asm volatile("global_load_dwordx4 %0, %1, off sc0\n\t"
               "s_waitcnt vmcnt(0)"
               : "=&v"(a) : "v"(p) : "memory");
}
__device__ __forceinline__ void st_chunk_sc0(fx4* p, fx4 v){
  asm volatile("global_store_dwordx4 %0, %1, off sc0" :: "v"(p), "v"(v) : "memory");
}

__device__ __forceinline__ float red32(float v){
  v += __shfl_xor(v, 16); v += __shfl_xor(v, 8); v += __shfl_xor(v, 4);
  v += __shfl_xor(v, 2);  v += __shfl_xor(v, 1);
  return v;
}
__device__ __forceinline__ float redsum64(float v){
  v += __shfl_xor(v, 32); v += __shfl_xor(v, 16); v += __shfl_xor(v, 8);
  v += __shfl_xor(v, 4);  v += __shfl_xor(v, 2);  v += __shfl_xor(v, 1);
  return v;
}
__device__ __forceinline__ float redmax64(float v){
  v = fmaxf(v, __shfl_xor(v, 32)); v = fmaxf(v, __shfl_xor(v, 16));
  v = fmaxf(v, __shfl_xor(v, 8));  v = fmaxf(v, __shfl_xor(v, 4));
  v = fmaxf(v, __shfl_xor(v, 2));  v = fmaxf(v, __shfl_xor(v, 1));
  return v;
}

// ---------------- pack: Wstack[1025][1280], row 1024 = bias row ----------------
__global__ void pack_kernel(const float* __restrict__ Wxh, const float* __restrict__ bh,
                            const float* __restrict__ Wc,  const float* __restrict__ bc,
                            const float* __restrict__ Wrp, const float* __restrict__ brp,
                            const float* __restrict__ Wwp, const float* __restrict__ bwp,
                            const float* __restrict__ Wrg, const float* __restrict__ brg,
                            const float* __restrict__ Wwg, const float* __restrict__ bwg,
                            float* __restrict__ Wstack, int* __restrict__ ctrl)
{
  // reset the XCD-gather control block every launch/replay
  if (blockIdx.x == 0 && blockIdx.y == 0 && threadIdx.x < 9)
    ctrl[threadIdx.x] = (threadIdx.x == 8) ? -1 : 0;

  int n = blockIdx.x*256 + threadIdx.x;
  int k = blockIdx.y;
  if (n >= GSTRIDE) return;
  float v = 0.f;
  if (k < II) {
    if (n < 512)       v = Wxh[k*512 + n];
    else if (n < 1024) v = Wc[k*512 + (n-512)];
    else if (n < 1124) v = Wrp[k*100 + (n-1024)];
    else if (n < 1224) v = Wwp[k*100 + (n-1124)];
    else if (n == 1224) v = Wrg[k];
    else if (n == 1225) v = Wwg[k];
  } else {
    if (n < 512)       v = bh[n];
    else if (n < 1024) v = bc[n-512];
    else if (n < 1124) v = brp[n-1024];
    else if (n < 1224) v = bwp[n-1124];
    else if (n == 1224) v = brg[0];
    else if (n == 1225) v = bwg[0];
  }
  Wstack[k*GSTRIDE + n] = v;
}

// ---------------- GEMM: G = X(32768x1024) @ Wstack(1024x1280) + bias, bf16 out ----------------
__global__ __launch_bounds__(256) void gemm_kernel(const float* __restrict__ X,
                                                   const float* __restrict__ Wstack,
                                                   __hip_bfloat16* __restrict__ G)
{
  __shared__ float As[16][68];
  __shared__ float Bs[16][64];
  const int tid = threadIdx.x;
  const int row0 = blockIdx.y*64, col0 = blockIdx.x*64;
  const int ty = tid>>4, tx = tid&15;
  const int amm = tid>>2, akk = (tid&3)<<2;
  const int bkk = tid>>4, bnn = (tid&15)<<2;
  float acc[4][4] = {{0.f}};
  for (int k0 = 0; k0 < II; k0 += 16) {
    float4 av = *(const float4*)(X + (size_t)(row0+amm)*II + k0 + akk);
    float4 bv = *(const float4*)(Wstack + (size_t)(k0+bkk)*GSTRIDE + col0 + bnn);
    __syncthreads();
    As[akk+0][amm]=av.x; As[akk+1][amm]=av.y; As[akk+2][amm]=av.z; As[akk+3][amm]=av.w;
    *(float4*)&Bs[bkk][bnn] = bv;
    __syncthreads();
#pragma unroll
    for (int kk=0; kk<16; kk++){
      float4 a = *(float4*)&As[kk][ty<<2];
      float4 b = *(float4*)&Bs[kk][tx<<2];
      acc[0][0] += a.x*b.x; acc[0][1] += a.x*b.y; acc[0][2] += a.x*b.z; acc[0][3] += a.x*b.w;
      acc[1][0] += a.y*b.x; acc[1][1] += a.y*b.y; acc[1][2] += a.y*b.z; acc[1][3] += a.y*b.w;
      acc[2][0] += a.z*b.x; acc[2][1] += a.z*b.y; acc[2][2] += a.z*b.z; acc[2][3] += a.z*b.w;
      acc[3][0] += a.w*b.x; acc[3][1] += a.w*b.y; acc[3][2] += a.w*b.z; acc[3][3] += a.w*b.w;
    }
  }
#pragma unroll
  for (int i2=0;i2<4;i2++){
    int r = row0 + (ty<<2) + i2;
#pragma unroll
    for (int j2=0;j2<4;j2++){
      int cidx = col0 + (tx<<2) + j2;
      float v = acc[i2][j2] + Wstack[(size_t)II*GSTRIDE + cidx];
      G[(size_t)r*GSTRIDE + cidx] = __float2bfloat16(v);
    }
  }
}

// ---------------- persistent sequential kernel ----------------
// 256 WGs launched (1/CU via LDS pad); runtime gather picks the 32 WGs of one
// XCD -> ring communicates through that XCD's shared L2 (sc0 fast path) with
// a device-scope sc1 backup buffer (dual store; consumers self-calibrate).
__global__ __launch_bounds__(TSEQ, 2) void seq_kernel(
    const float* __restrict__ Wc,  const float* __restrict__ Wwg,
    const float* __restrict__ Wwp, const float* __restrict__ Wrg,
    const float* __restrict__ Wrp, const float* __restrict__ Wrh,
    const float* __restrict__ Whh,
    const __hip_bfloat16* __restrict__ G,
    float* __restrict__ out,
    fx4* rec_fast, fx4* rec_slow, int* ctrl, int N)
{
  const int t = threadIdx.x;

  // de-chunked record staging: row = source WG, [0..15]=h, [16..31]=c, [32..35]=wp
  __shared__ __align__(16) float rec_f[NWG][40];
  __shared__ float pubbuf[36];
  __shared__ float e_ar[104], aw_n[104];
  __shared__ float part_ar[4][104];
  __shared__ float part2[4][128];
  __shared__ float memW[JW][104];
  __shared__ float Wwp_sl[4][HH];
  __shared__ float scal_s[2];
  __shared__ int rank_s;
  __shared__ char pad[72*1024];   // forces 1 WG/CU (25KB + 72KB > 80KB)
  if (N == -2147483647) ((volatile char*)pad)[t] = 1;   // keep pad allocated

  // ---- XCD gather: first XCD to assemble 32 WGs wins; others exit ----
  if (t == 0) {
    unsigned xcc;
    asm volatile("s_getreg_b32 %0, hwreg(HW_REG_XCC_ID)" : "=s"(xcc));
    xcc &= 7u;
    int slot = atomicAdd(&ctrl[xcc], 1);
    int r = -1;
    if (slot < NWG) {
      if (slot == NWG-1) atomicCAS(&ctrl[8], -1, (int)xcc);
      int wv;
      do { wv = __hip_atomic_load(&ctrl[8], __ATOMIC_RELAXED, __HIP_MEMORY_SCOPE_AGENT); }
      while (wv == -1);
      if (wv == (int)xcc) r = slot;
    }
    rank_s = r;
  }
  __syncthreads();
  const int w = rank_s;
  if (w < 0) return;

  const int j = t >> 5;        // 0..15 local column
  const int l = t & 31;
  const int jg = w*JW + j;     // global h column

  // register-resident column slices: Whh[:,jg], Wc_h[:,jg], Wrh[:,jg]
  float whh_r[16], wch_r[16], wrh_r[16];
#pragma unroll
  for (int i=0;i<16;i++){
    int k = i*32 + l;
    whh_r[i] = Whh[(size_t)k*HH + jg];
    wch_r[i] = Wc[(size_t)(II+k)*HH + jg];
    wrh_r[i] = Wrh[(size_t)k*HH + jg];
  }
  // consumer-side ar weights: thread (q=t/101, m=t%101) holds Wrp_h[q*128+i][m]
  const int mq_m = t % 101;
  const int mq_q = t / 101;
  float wrp_r[128];
  if (t < 404) {
#pragma unroll
    for (int i=0;i<128;i++){
      int kg = II + mq_q*128 + i;
      wrp_r[i] = (mq_m < 100) ? Wrp[(size_t)kg*100 + mq_m] : Wrg[kg];
    }
  }
  for (int idx=t; idx<JW*104; idx+=TSEQ){
    int kl = idx/104, m = idx - kl*104;
    memW[kl][m] = 0.f;
  }
  for (int idx=t; idx<4*HH; idx+=TSEQ){
    int ci = idx>>9, k = idx&511;
    int cg = ci*32 + w;
    float v = 0.f;
    if (cg < 100) v = Wwp[(size_t)(II+k)*100 + cg];
    else if (cg == 100) v = Wwg[II+k];
    Wwp_sl[ci][k] = v;
  }
  if (t < 36) pubbuf[t] = 0.f;
  __syncthreads();

  // ---- step 0: h0 = relu(G_xh[0]), c0 = relu(G_c[0]); wp logits(h_-1=0)=0 ----
  if (t < JW) {
    float hv = fmaxf(0.f, bf2f(G[(size_t)0*GSTRIDE + w*JW + t]));
    float cv = fmaxf(0.f, bf2f(G[(size_t)0*GSTRIDE + 512 + w*JW + t]));
    pubbuf[t] = hv;
    pubbuf[16+t] = cv;
    out[(size_t)0*HH + w*JW + t] = hv;
  }
  __syncthreads();
  if (t < CHK) {
    fx4 v;
    v.x = pubbuf[3*t]; v.y = pubbuf[3*t+1]; v.z = pubbuf[3*t+2];
    v.w = u2f(1u);
    st_chunk_sc0(rec_fast + (size_t)w*CHK + t, v);
    st_chunk_sc1(rec_slow + (size_t)w*CHK + t, v);
  }

  int fast_ok = 1, fast_fail = 0;

  for (int step=1; step<N; ++step) {
    const unsigned tg = (unsigned)step;
    // (A) prefetch this step's G values into registers
    float g_rp0=0.f, g_rp1=0.f, g_aw0=0.f, g_aw1=0.f, g_h=0.f, g_c=0.f;
    {
      const __hip_bfloat16* Grow = G + (size_t)step*GSTRIDE;
      if (t < 64) {
        g_rp0 = bf2f(Grow[1024+t]);
        int m2 = t+64;
        g_rp1 = bf2f(Grow[m2==100 ? 1224 : 1024+m2]);
      } else if (t < 128) {
        const __hip_bfloat16* Gpr = G + (size_t)(step-1)*GSTRIDE;
        int u = t-64;
        g_aw0 = bf2f(Gpr[1124+u]);
        int m2 = u+64;
        g_aw1 = bf2f(Gpr[m2==100 ? 1225 : 1124+m2]);
      }
      if (l == 0) { g_h = bf2f(Grow[jg]); g_c = bf2f(Grow[512+jg]); }
    }
    // (B) spin-load step-1 records: fast sc0 (XCD L2) with bounded spin,
    //     sc1 (IC) fallback; self-calibrating per thread
    if (t < NWG*CHK) {
      const size_t ridx = (size_t)((step&1)^1)*NWG*CHK + t;
      const fx4* pf = rec_fast + ridx;
      const fx4* ps = rec_slow + ridx;
      fx4 a; int got = 0;
      if (fast_ok) {
        for (int it=0; it<64; ++it){
          ld_chunk_sc0(pf, a);
          if (f2u(a.w) == tg) { got = 1; break; }
        }
      }
      if (!got) {
        ld_chunk_sc1(ps, a);
        while (f2u(a.w) != tg) ld_chunk_sc1(ps, a);
        if (fast_ok) {
          // discriminate: slow delivered — does fast have it now?
          fx4 a2; ld_chunk_sc0(pf, a2);
          if (f2u(a2.w) == tg) fast_fail = 0;
          else if (++fast_fail >= 8) fast_ok = 0;
        }
      } else fast_fail = 0;
      int wgsrc = t / CHK, ci = t - wgsrc*CHK;
      float* dst = &rec_f[wgsrc][3*ci];
      dst[0] = a.x; dst[1] = a.y; dst[2] = a.z;
    }
    __syncthreads();   // b1: rec_f complete
    // (C1) consumer-side ar logits: part_ar[q][m] = sum_{k=q*128..+127} h[k]*Wrp_h[k][m]
    if (t < 404) {
      float s0=0.f, s1=0.f, s2=0.f, s3=0.f;
#pragma unroll
      for (int bw=0; bw<8; bw++){
        const fx4* hp = (const fx4*)&rec_f[mq_q*8 + bw][0];
#pragma unroll
        for (int ii=0; ii<4; ii++){
          fx4 h4 = hp[ii];
          s0 += h4.x*wrp_r[bw*16 + ii*4 + 0];
          s1 += h4.y*wrp_r[bw*16 + ii*4 + 1];
          s2 += h4.z*wrp_r[bw*16 + ii*4 + 2];
          s3 += h4.w*wrp_r[bw*16 + ii*4 + 3];
        }
      }
      part_ar[mq_q][mq_m] = (s0+s1)+(s2+s3);
    }
    // (C2) register matvecs ph/pc/pw (broadcast LDS reads, conflict-free)
    float ph=0.f, pc=0.f, pw=0.f;
    {
#pragma unroll
      for (int i=0;i<16;i++){
        int k = i*32 + l;
        float hv  = rec_f[k>>4][k&15];
        float cv2 = rec_f[k>>4][16+(k&15)];
        ph += whh_r[i]*hv;
        pc += wch_r[i]*hv;
        pw += wrh_r[i]*cv2;
      }
      ph = red32(ph); pc = red32(pc); pw = red32(pw);
    }
    // (C3) wp partial dots (producer role for next step)
    {
      int ci = t >> 7, li = t & 127;
      float s = 0.f;
#pragma unroll
      for (int ii=0; ii<4; ii++){
        int k = li + 128*ii;
        s += rec_f[k>>4][k&15] * Wwp_sl[ci][k];
      }
      part2[ci][li] = s;
    }
    __syncthreads();   // b2: part_ar/part2 ready
    // (D) wave0: ar softmax; wave1: aw softmax; waves2-5: wp logit reduce
    if (t < 64) {
      int u = t, m2 = u+64;
      float v0 = part_ar[0][u]+part_ar[1][u]+part_ar[2][u]+part_ar[3][u] + g_rp0;
      float v1 = (m2 <= 100) ? (part_ar[0][m2]+part_ar[1][m2]+part_ar[2][m2]+part_ar[3][m2] + g_rp1)
                             : -1e30f;
      float vs1 = (m2 < 100) ? v1 : -1e30f;
      float mx = redmax64(fmaxf(v0, vs1));
      float e0 = __expf(v0 - mx), e1 = __expf(vs1 - mx);
      e_ar[u] = e0;
      if (m2 < 104) e_ar[m2] = e1;
      float ssum = redsum64(e0 + e1);
      float r100 = __shfl(v1, 36);
      if (u == 0) scal_s[0] = (1.f/(1.f+__expf(-r100))) / ssum;
    } else if (t < 128) {
      int u = t-64, m2 = u+64;
      float v0 = rec_f[u&31][32+(u>>5)] + g_aw0;
      float v1 = -1e30f;
      if (m2 <= 100) v1 = rec_f[m2&31][32+(m2>>5)] + g_aw1;
      float vs1 = (m2 < 100) ? v1 : -1e30f;
      float mx = redmax64(fmaxf(v0, vs1));
      float e0 = __expf(v0 - mx), e1 = __expf(vs1 - mx);
      float ssum = redsum64(e0 + e1);
      aw_n[u] = e0 / ssum;
      if (m2 < 104) aw_n[m2] = e1 / ssum;
      float r100 = __shfl(v1, 36);
      if (u == 0) scal_s[1] = 1.f/(1.f+__expf(-r100));
    } else if (t < 384) {
      int wv = t >> 6;           // 2..5
      int ci = wv - 2, ln = t & 63;
      float s = part2[ci][ln] + part2[ci][ln+64];
      s = redsum64(s);
      if (ln == 0 && (ci*32 + w) < 101) pubbuf[32+ci] = s;
    }
    __syncthreads();   // b3: e_ar/aw_n/scal/pubbuf.wp ready
    // (E) memW update fused with rW accumulation; h/c finalize
    {
      float gws = scal_s[1], gos = scal_s[0];
      float rwp = 0.f;
#pragma unroll
      for (int q=0; q<4; q++){
        int m = l + 32*q;
        if (m < 100) {
          float a2 = aw_n[m];
          float mv = memW[j][m];
          mv = (1.f - a2)*mv + gws*a2*pw;
          memW[j][m] = mv;
          rwp += e_ar[m]*mv;
        }
      }
      rwp = red32(rwp);
      float hv = fmaxf(0.f, g_h + ph + gos*rwp);
      if (l == 0) {
        float cv = fmaxf(0.f, g_c + pc);
        pubbuf[j] = hv;
        pubbuf[16+j] = cv;
        out[(size_t)step*HH + jg] = hv;
      }
    }
    if (step + 1 < N) {
      __syncthreads();   // b4: pubbuf h,c ready (wp set in (D))
      // (G) wave0 packs + fires tagged chunks to both buffers (fast first)
      if (t < CHK) {
        fx4 v;
        v.x = pubbuf[3*t]; v.y = pubbuf[3*t+1]; v.z = pubbuf[3*t+2];
        v.w = u2f((unsigned)(step+1));
        size_t ridx = (size_t)((step&1)*NWG + w)*CHK + t;
        st_chunk_sc0(rec_fast + ridx, v);
        st_chunk_sc1(rec_slow + ridx, v);
      }
    }
  }
}

extern "C" void kernel_launch(void* const* d_in, const int* in_sizes, int n_in,
                              void* d_out, int out_size, void* d_ws, size_t ws_size,
                              hipStream_t stream) {
  const float* X   = (const float*)d_in[0];
  const float* Wc  = (const float*)d_in[1];
  const float* bc  = (const float*)d_in[2];
  const float* Wwg = (const float*)d_in[3];
  const float* bwg = (const float*)d_in[4];
  const float* Wwp = (const float*)d_in[5];
  const float* bwp = (const float*)d_in[6];
  const float* Wrg = (const float*)d_in[7];
  const float* brg = (const float*)d_in[8];
  const float* Wrp = (const float*)d_in[9];
  const float* brp = (const float*)d_in[10];
  const float* Wxh = (const float*)d_in[11];
  const float* Wrh = (const float*)d_in[12];
  const float* Whh = (const float*)d_in[13];
  const float* bh  = (const float*)d_in[14];

  const int N = in_sizes[0] / II;   // 32768

  char* ws = (char*)d_ws;
  int* ctrl = (int*)ws;
  fx4* rec_fast = (fx4*)(ws + OFF_RECF);
  fx4* rec_slow = (fx4*)(ws + OFF_RECS);
  float* Wstack = (float*)(ws + OFF_WSTACK);
  __hip_bfloat16* G = (__hip_bfloat16*)(ws + OFF_G);
  float* out = (float*)d_out;

  pack_kernel<<<dim3(GSTRIDE/256, II+1), 256, 0, stream>>>(
      Wxh, bh, Wc, bc, Wrp, brp, Wwp, bwp, Wrg, brg, Wwg, bwg, Wstack, ctrl);

  gemm_kernel<<<dim3(GSTRIDE/64, N/64), 256, 0, stream>>>(X, Wstack, G);

  seq_kernel<<<NWGL, TSEQ, 0, stream>>>(
      Wc, Wwg, Wwp, Wrg, Wrp, Wrh, Whh, G, out,
      rec_fast, rec_slow, ctrl, N);
}

// Round 4
// 113555.005 us; speedup vs baseline: 2.4787x; 2.4787x over previous
//
#include <hip/hip_runtime.h>
#include <hip/hip_bf16.h>

#define NWG 32
#define TSEQ 512
#define JW 16          // h-columns per WG
#define HH 512
#define II 1024
#define GSTRIDE 1280   // padded row stride of G (floats/bf16 elements)
#define REC 48         // record stride in 16B chunks
#define CHK1 12        // group-1 chunks: 36 floats = h[16]+c[16]+wp[4]
#define CHK2 34        // group-2 chunks: 102 floats = rp[101]+pad

// workspace byte offsets
#define OFF_REC    4096u                       // 2*32*48*16B = 48 KB
#define OFF_WSTACK (1u<<20)                    // 1025*1280 f32 ~ 5.25 MB
#define OFF_G      (16u<<20)                   // N*1280 bf16 ~ 84 MB

typedef float fx4 __attribute__((ext_vector_type(4)));

__device__ __forceinline__ float bf2f(__hip_bfloat16 x){ return __bfloat162float(x); }
__device__ __forceinline__ unsigned f2u(float x){ return __builtin_bit_cast(unsigned, x); }
__device__ __forceinline__ float u2f(unsigned x){ return __builtin_bit_cast(float, x); }

// sc1: device-coherent at Infinity Cache (proven transport)
__device__ __forceinline__ void ld_chunk1(const fx4* p, fx4& a){
  asm volatile("global_load_dwordx4 %0, %1, off sc1\n\t"
               "s_waitcnt vmcnt(0)"
               : "=&v"(a) : "v"(p) : "memory");
}
__device__ __forceinline__ void ld_chunk_async(const fx4* p, fx4& a){
  asm volatile("global_load_dwordx4 %0, %1, off sc1" : "=&v"(a) : "v"(p) : "memory");
}
__device__ __forceinline__ void wait_vm3(fx4& a, fx4& b, fx4& c){
  asm volatile("s_waitcnt vmcnt(0)" : "+v"(a), "+v"(b), "+v"(c) :: "memory");
}
__device__ __forceinline__ void st_chunk(fx4* p, fx4 v){
  asm volatile("global_store_dwordx4 %0, %1, off sc1" :: "v"(p), "v"(v) : "memory");
}

__device__ __forceinline__ float red32(float v){
  v += __shfl_xor(v, 16); v += __shfl_xor(v, 8); v += __shfl_xor(v, 4);
  v += __shfl_xor(v, 2);  v += __shfl_xor(v, 1);
  return v;
}
__device__ __forceinline__ float redsum64(float v){
  v += __shfl_xor(v, 32); v += __shfl_xor(v, 16); v += __shfl_xor(v, 8);
  v += __shfl_xor(v, 4);  v += __shfl_xor(v, 2);  v += __shfl_xor(v, 1);
  return v;
}
__device__ __forceinline__ float redmax64(float v){
  v = fmaxf(v, __shfl_xor(v, 32)); v = fmaxf(v, __shfl_xor(v, 16));
  v = fmaxf(v, __shfl_xor(v, 8));  v = fmaxf(v, __shfl_xor(v, 4));
  v = fmaxf(v, __shfl_xor(v, 2));  v = fmaxf(v, __shfl_xor(v, 1));
  return v;
}

// ---------------- pack: Wstack[1025][1280], row 1024 = bias row ----------------
__global__ void pack_kernel(const float* __restrict__ Wxh, const float* __restrict__ bh,
                            const float* __restrict__ Wc,  const float* __restrict__ bc,
                            const float* __restrict__ Wrp, const float* __restrict__ brp,
                            const float* __restrict__ Wwp, const float* __restrict__ bwp,
                            const float* __restrict__ Wrg, const float* __restrict__ brg,
                            const float* __restrict__ Wwg, const float* __restrict__ bwg,
                            float* __restrict__ Wstack)
{
  int n = blockIdx.x*256 + threadIdx.x;
  int k = blockIdx.y;
  if (n >= GSTRIDE) return;
  float v = 0.f;
  if (k < II) {
    if (n < 512)       v = Wxh[k*512 + n];
    else if (n < 1024) v = Wc[k*512 + (n-512)];
    else if (n < 1124) v = Wrp[k*100 + (n-1024)];
    else if (n < 1224) v = Wwp[k*100 + (n-1124)];
    else if (n == 1224) v = Wrg[k];
    else if (n == 1225) v = Wwg[k];
  } else {
    if (n < 512)       v = bh[n];
    else if (n < 1024) v = bc[n-512];
    else if (n < 1124) v = brp[n-1024];
    else if (n < 1224) v = bwp[n-1124];
    else if (n == 1224) v = brg[0];
    else if (n == 1225) v = bwg[0];
  }
  Wstack[k*GSTRIDE + n] = v;
}

// ---------------- GEMM: G = X(32768x1024) @ Wstack(1024x1280) + bias, bf16 out ----------------
__global__ __launch_bounds__(256) void gemm_kernel(const float* __restrict__ X,
                                                   const float* __restrict__ Wstack,
                                                   __hip_bfloat16* __restrict__ G)
{
  __shared__ float As[16][68];
  __shared__ float Bs[16][64];
  const int tid = threadIdx.x;
  const int row0 = blockIdx.y*64, col0 = blockIdx.x*64;
  const int ty = tid>>4, tx = tid&15;
  const int amm = tid>>2, akk = (tid&3)<<2;
  const int bkk = tid>>4, bnn = (tid&15)<<2;
  float acc[4][4] = {{0.f}};
  for (int k0 = 0; k0 < II; k0 += 16) {
    float4 av = *(const float4*)(X + (size_t)(row0+amm)*II + k0 + akk);
    float4 bv = *(const float4*)(Wstack + (size_t)(k0+bkk)*GSTRIDE + col0 + bnn);
    __syncthreads();
    As[akk+0][amm]=av.x; As[akk+1][amm]=av.y; As[akk+2][amm]=av.z; As[akk+3][amm]=av.w;
    *(float4*)&Bs[bkk][bnn] = bv;
    __syncthreads();
#pragma unroll
    for (int kk=0; kk<16; kk++){
      float4 a = *(float4*)&As[kk][ty<<2];
      float4 b = *(float4*)&Bs[kk][tx<<2];
      acc[0][0] += a.x*b.x; acc[0][1] += a.x*b.y; acc[0][2] += a.x*b.z; acc[0][3] += a.x*b.w;
      acc[1][0] += a.y*b.x; acc[1][1] += a.y*b.y; acc[1][2] += a.y*b.z; acc[1][3] += a.y*b.w;
      acc[2][0] += a.z*b.x; acc[2][1] += a.z*b.y; acc[2][2] += a.z*b.z; acc[2][3] += a.z*b.w;
      acc[3][0] += a.w*b.x; acc[3][1] += a.w*b.y; acc[3][2] += a.w*b.z; acc[3][3] += a.w*b.w;
    }
  }
#pragma unroll
  for (int i2=0;i2<4;i2++){
    int r = row0 + (ty<<2) + i2;
#pragma unroll
    for (int j2=0;j2<4;j2++){
      int cidx = col0 + (tx<<2) + j2;
      float v = acc[i2][j2] + Wstack[(size_t)II*GSTRIDE + cidx];
      G[(size_t)r*GSTRIDE + cidx] = __float2bfloat16(v);
    }
  }
}

// ---------------- persistent sequential kernel ----------------
// Round-1 transport (sc1 tagged chunks, producer-side rp in LDS) with
// SPLIT publish: group-1 (h/c/wp) fires right after h finalize; group-2
// (rp partials) fires after F. Consumers overlap the heavy matvecs with
// group-2 flight (async issue -> compute -> wait/retry).
__global__ __launch_bounds__(TSEQ) void seq_kernel(
    const float* __restrict__ Wc,  const float* __restrict__ Wwg,
    const float* __restrict__ Wwp, const float* __restrict__ Wrg,
    const float* __restrict__ Wrp, const float* __restrict__ Wrh,
    const float* __restrict__ Whh,
    const __hip_bfloat16* __restrict__ G,
    float* __restrict__ out,
    fx4* rec4, int N)
{
  const int w = blockIdx.x;
  const int t = threadIdx.x;
  const int j = t >> 5;        // 0..15 local column
  const int l = t & 31;
  const int jg = w*JW + j;     // global h column

  // group-1 staging: row = source WG, [0..15]=h, [16..31]=c, [32..35]=wp (pad to 40)
  __shared__ __align__(16) float raw1[NWG][40];
  // group-2 staging: row = source WG, rp partials [0..100] (pad to 104)
  __shared__ float raw2[NWG][104];
  __shared__ float pubbuf[36];
  __shared__ float pub2[104];
  __shared__ float ht[JW];
  __shared__ float e_ar[104], aw_n[104];
  __shared__ float part6[4][104];
  __shared__ float part2[4][128];
  __shared__ float memW[JW][104];
  __shared__ float Wrp_sl[JW][104];
  __shared__ float Wwp_sl[4][HH];
  __shared__ float scal_s[2];

  // register-resident column slices: Whh[:,jg], Wc_h[:,jg], Wrh[:,jg]
  float whh_r[16], wch_r[16], wrh_r[16];
#pragma unroll
  for (int i=0;i<16;i++){
    int k = i*32 + l;
    whh_r[i] = Whh[(size_t)k*HH + jg];
    wch_r[i] = Wc[(size_t)(II+k)*HH + jg];
    wrh_r[i] = Wrh[(size_t)k*HH + jg];
  }
  for (int idx=t; idx<JW*104; idx+=TSEQ){
    int kl = idx/104, m = idx - kl*104;
    int kgl = II + w*JW + kl;
    float v = 0.f;
    if (m < 100) v = Wrp[(size_t)kgl*100 + m];
    else if (m == 100) v = Wrg[kgl];
    Wrp_sl[kl][m] = v;
    memW[kl][m] = 0.f;
  }
  for (int idx=t; idx<4*HH; idx+=TSEQ){
    int ci = idx>>9, k = idx&511;
    int cg = ci*32 + w;
    float v = 0.f;
    if (cg < 100) v = Wwp[(size_t)(II+k)*100 + cg];
    else if (cg == 100) v = Wwg[II+k];
    Wwp_sl[ci][k] = v;
  }
  if (t < 36) pubbuf[t] = 0.f;
  if (t < 104) pub2[t] = 0.f;
  __syncthreads();

  // ---- step 0: h0 = relu(G_xh[0]), c0 = relu(G_c[0]); wp logits(h_-1=0)=0 ----
  if (t < JW) {
    float hv = fmaxf(0.f, bf2f(G[(size_t)0*GSTRIDE + w*JW + t]));
    float cv = fmaxf(0.f, bf2f(G[(size_t)0*GSTRIDE + 512 + w*JW + t]));
    ht[t] = hv;
    pubbuf[t] = hv;
    pubbuf[16+t] = cv;
    out[(size_t)0*HH + w*JW + t] = hv;
  }
  __syncthreads();
  if (t < 101) {
    float s = 0.f;
#pragma unroll
    for (int kl=0; kl<16; kl++) s += ht[kl]*Wrp_sl[kl][t];
    pub2[t] = s;
  }
  __syncthreads();
  if (t < CHK1) {
    fx4 v; v.x = pubbuf[3*t]; v.y = pubbuf[3*t+1]; v.z = pubbuf[3*t+2];
    v.w = u2f(1u);
    st_chunk(rec4 + (size_t)w*REC + t, v);
  }
  if (t < CHK2) {
    fx4 v; v.x = pub2[3*t]; v.y = pub2[3*t+1]; v.z = pub2[3*t+2];
    v.w = u2f(1u);
    st_chunk(rec4 + (size_t)w*REC + CHK1 + t, v);
  }

  // loop-invariant group-2 chunk assignment: qa=t, qb=t+512, qc=t+1024 (t<64)
  const int wA = t/CHK2,        cjA = t - wA*CHK2;
  const int wB = (t+512)/CHK2,  cjB = (t+512) - wB*CHK2;
  const int wC = (t+1024)/CHK2, cjC = (t+1024) - wC*CHK2;   // valid only t<64
  const int offA = wA*REC + CHK1 + cjA;
  const int offB = wB*REC + CHK1 + cjB;
  const int offC = wC*REC + CHK1 + cjC;

  for (int step=1; step<N; ++step) {
    const unsigned tg = (unsigned)step;
    // (A) prefetch this step's G values into registers
    float g_rp0=0.f, g_rp1=0.f, g_aw0=0.f, g_aw1=0.f, g_h=0.f, g_c=0.f;
    {
      const __hip_bfloat16* Grow = G + (size_t)step*GSTRIDE;
      if (t < 64) {
        g_rp0 = bf2f(Grow[1024+t]);
        int m2 = t+64;
        g_rp1 = bf2f(Grow[m2==100 ? 1224 : 1024+m2]);
      } else if (t < 128) {
        const __hip_bfloat16* Gpr = G + (size_t)(step-1)*GSTRIDE;
        int u = t-64;
        g_aw0 = bf2f(Gpr[1124+u]);
        int m2 = u+64;
        g_aw1 = bf2f(Gpr[m2==100 ? 1225 : 1124+m2]);
      }
      if (l == 0) { g_h = bf2f(Grow[jg]); g_c = bf2f(Grow[512+jg]); }
    }
    const fx4* prev4 = rec4 + (size_t)((step&1)^1)*NWG*REC;
    // (B1) spin group-1 (h/c/wp): t<384 one chunk each
    if (t < NWG*CHK1) {
      int sw = t / CHK1, ci = t - sw*CHK1;
      const fx4* p = prev4 + sw*REC + ci;
      fx4 a;
      ld_chunk1(p, a);
      while (f2u(a.w) != tg) ld_chunk1(p, a);
      float* dst = &raw1[sw][3*ci];
      dst[0] = a.x; dst[1] = a.y; dst[2] = a.z;
    }
    __syncthreads();   // b1a: raw1 complete
    // (B2-issue) async group-2 loads (2/thread, 3 for t<64)
    fx4 a0, a1, a2 = {0.f,0.f,0.f,0.f};
    const fx4 *pA = prev4 + offA, *pB = prev4 + offB, *pC = prev4 + offC;
    ld_chunk_async(pA, a0);
    ld_chunk_async(pB, a1);
    if (t < 64) ld_chunk_async(pC, a2);
    // (C2) register matvecs ph/pc/pw (broadcast LDS reads, conflict-free)
    float ph=0.f, pc=0.f, pw=0.f;
    {
#pragma unroll
      for (int i=0;i<16;i++){
        int k = i*32 + l;
        float hv  = raw1[k>>4][k&15];
        float cv2 = raw1[k>>4][16+(k&15)];
        ph += whh_r[i]*hv;
        pc += wch_r[i]*hv;
        pw += wrh_r[i]*cv2;
      }
      ph = red32(ph); pc = red32(pc); pw = red32(pw);
    }
    // (C3) wp partial dots (producer role for next step)
    {
      int ci = t >> 7, li = t & 127;
      float s = 0.f;
#pragma unroll
      for (int ii=0; ii<4; ii++){
        int k = li + 128*ii;
        s += raw1[k>>4][k&15] * Wwp_sl[ci][k];
      }
      part2[ci][li] = s;
    }
    // (B2-wait) drain async loads; retry any stale chunk; de-chunk raw2
    {
      wait_vm3(a0, a1, a2);
      while (f2u(a0.w) != tg) ld_chunk1(pA, a0);
      while (f2u(a1.w) != tg) ld_chunk1(pB, a1);
      if (t < 64) { while (f2u(a2.w) != tg) ld_chunk1(pC, a2); }
      float* d0 = &raw2[wA][3*cjA]; d0[0]=a0.x; d0[1]=a0.y; d0[2]=a0.z;
      float* d1 = &raw2[wB][3*cjB]; d1[0]=a1.x; d1[1]=a1.y; d1[2]=a1.z;
      if (t < 64) { float* d2 = &raw2[wC][3*cjC]; d2[0]=a2.x; d2[1]=a2.y; d2[2]=a2.z; }
    }
    __syncthreads();   // b1b: raw2 complete
    // (C1) merge rp partials across 8-record groups
    if (t < 404) {
      int m = t % 101, q = t / 101;
      const float* b = &raw2[q*8][0] + m;
      float s = ((b[0]+b[104])+(b[208]+b[312])) + ((b[416]+b[520])+(b[624]+b[728]));
      part6[q][m] = s;
    }
    __syncthreads();   // b2: part6/part2 ready
    // (D) wave0: ar softmax; wave1: aw softmax; waves2-5: wp logit reduce
    if (t < 64) {
      int u = t, m2 = u+64;
      float v0 = part6[0][u]+part6[1][u]+part6[2][u]+part6[3][u] + g_rp0;
      float v1 = (m2 <= 100) ? (part6[0][m2]+part6[1][m2]+part6[2][m2]+part6[3][m2] + g_rp1)
                             : -1e30f;
      float vs1 = (m2 < 100) ? v1 : -1e30f;
      float mx = redmax64(fmaxf(v0, vs1));
      float e0 = __expf(v0 - mx), e1 = __expf(vs1 - mx);
      e_ar[u] = e0;
      if (m2 < 104) e_ar[m2] = e1;
      float ssum = redsum64(e0 + e1);
      float r100 = __shfl(v1, 36);
      if (u == 0) scal_s[0] = (1.f/(1.f+__expf(-r100))) / ssum;
    } else if (t < 128) {
      int u = t-64, m2 = u+64;
      float v0 = raw1[u&31][32+(u>>5)] + g_aw0;
      float v1 = -1e30f;
      if (m2 <= 100) v1 = raw1[m2&31][32+(m2>>5)] + g_aw1;
      float vs1 = (m2 < 100) ? v1 : -1e30f;
      float mx = redmax64(fmaxf(v0, vs1));
      float e0 = __expf(v0 - mx), e1 = __expf(vs1 - mx);
      float ssum = redsum64(e0 + e1);
      aw_n[u] = e0 / ssum;
      if (m2 < 104) aw_n[m2] = e1 / ssum;
      float r100 = __shfl(v1, 36);
      if (u == 0) scal_s[1] = 1.f/(1.f+__expf(-r100));
    } else if (t < 384) {
      int wv = t >> 6;           // 2..5
      int ci = wv - 2, ln = t & 63;
      float s = part2[ci][ln] + part2[ci][ln+64];
      s = redsum64(s);
      if (ln == 0 && (ci*32 + w) < 101) pubbuf[32+ci] = s;
    }
    __syncthreads();   // b3: e_ar/aw_n/scal/pubbuf.wp ready
    // (E) memW update fused with rW accumulation; h/c finalize
    {
      float gws = scal_s[1], gos = scal_s[0];
      float rwp = 0.f;
#pragma unroll
      for (int q=0; q<4; q++){
        int m = l + 32*q;
        if (m < 100) {
          float a2 = aw_n[m];
          float mv = memW[j][m];
          mv = (1.f - a2)*mv + gws*a2*pw;
          memW[j][m] = mv;
          rwp += e_ar[m]*mv;
        }
      }
      rwp = red32(rwp);
      float hv = fmaxf(0.f, g_h + ph + gos*rwp);
      if (l == 0) {
        float cv = fmaxf(0.f, g_c + pc);
        ht[j] = hv;
        pubbuf[j] = hv;
        pubbuf[16+j] = cv;
        out[(size_t)step*HH + jg] = hv;
      }
    }
    if (step + 1 < N) {
      __syncthreads();   // b4: ht / pubbuf h,c ready (wp set in D)
      // (G1) fire group-1 IMMEDIATELY (before F) — unblocks consumers early
      fx4* cur4 = rec4 + (size_t)((step&1)*NWG + w)*REC;
      if (t < CHK1) {
        fx4 v; v.x = pubbuf[3*t]; v.y = pubbuf[3*t+1]; v.z = pubbuf[3*t+2];
        v.w = u2f((unsigned)(step+1));
        st_chunk(cur4 + t, v);
      }
      // (F) rp partials for next step (concurrent with G1 on other threads)
      if (t < 101) {
        float s = 0.f;
#pragma unroll
        for (int kl=0; kl<16; kl++) s += ht[kl]*Wrp_sl[kl][t];
        pub2[t] = s;
      }
      __syncthreads();   // b5: pub2 complete
      // (G2) fire group-2
      if (t < CHK2) {
        fx4 v; v.x = pub2[3*t]; v.y = pub2[3*t+1]; v.z = pub2[3*t+2];
        v.w = u2f((unsigned)(step+1));
        st_chunk(cur4 + CHK1 + t, v);
      }
    }
  }
}

extern "C" void kernel_launch(void* const* d_in, const int* in_sizes, int n_in,
                              void* d_out, int out_size, void* d_ws, size_t ws_size,
                              hipStream_t stream) {
  const float* X   = (const float*)d_in[0];
  const float* Wc  = (const float*)d_in[1];
  const float* bc  = (const float*)d_in[2];
  const float* Wwg = (const float*)d_in[3];
  const float* bwg = (const float*)d_in[4];
  const float* Wwp = (const float*)d_in[5];
  const float* bwp = (const float*)d_in[6];
  const float* Wrg = (const float*)d_in[7];
  const float* brg = (const float*)d_in[8];
  const float* Wrp = (const float*)d_in[9];
  const float* brp = (const float*)d_in[10];
  const float* Wxh = (const float*)d_in[11];
  const float* Wrh = (const float*)d_in[12];
  const float* Whh = (const float*)d_in[13];
  const float* bh  = (const float*)d_in[14];

  const int N = in_sizes[0] / II;   // 32768

  char* ws = (char*)d_ws;
  fx4* rec4 = (fx4*)(ws + OFF_REC);
  float* Wstack = (float*)(ws + OFF_WSTACK);
  __hip_bfloat16* G = (__hip_bfloat16*)(ws + OFF_G);
  float* out = (float*)d_out;

  pack_kernel<<<dim3(GSTRIDE/256, II+1), 256, 0, stream>>>(
      Wxh, bh, Wc, bc, Wrp, brp, Wwp, bwp, Wrg, brg, Wwg, bwg, Wstack);

  gemm_kernel<<<dim3(GSTRIDE/64, N/64), 256, 0, stream>>>(X, Wstack, G);

  seq_kernel<<<NWG, TSEQ, 0, stream>>>(
      Wc, Wwg, Wwp, Wrg, Wrp, Wrh, Whh, G, out,
      rec4, N);
}

// Round 5
// 96142.279 us; speedup vs baseline: 2.9276x; 1.1811x over previous
//
#include <hip/hip_runtime.h>
#include <hip/hip_bf16.h>

#define NWG 32
#define TSEQ 512
#define JW 16          // h-columns per WG
#define HH 512
#define II 1024
#define GSTRIDE 1280   // padded row stride of G (floats/bf16 elements)
#define REC 48         // record stride in 16B chunks
#define CHK1 12        // group-1 chunks: 36 floats = h[16]+c[16]+wp[4]
#define CHK2 34        // group-2 chunks: 102 floats = rp[101]+pad

// workspace byte offsets
#define OFF_REC    4096u                       // 2*32*48*16B = 48 KB
#define OFF_WSTACK (1u<<20)                    // 1025*1280 f32 ~ 5.25 MB
#define OFF_G      (16u<<20)                   // N*1280 bf16 ~ 84 MB

typedef float fx4 __attribute__((ext_vector_type(4)));

__device__ __forceinline__ float bf2f(__hip_bfloat16 x){ return __bfloat162float(x); }
__device__ __forceinline__ unsigned f2u(float x){ return __builtin_bit_cast(unsigned, x); }
__device__ __forceinline__ float u2f(unsigned x){ return __builtin_bit_cast(float, x); }

// sc1: device-coherent at Infinity Cache (proven transport)
__device__ __forceinline__ void ld_chunk1(const fx4* p, fx4& a){
  asm volatile("global_load_dwordx4 %0, %1, off sc1\n\t"
               "s_waitcnt vmcnt(0)"
               : "=&v"(a) : "v"(p) : "memory");
}
__device__ __forceinline__ void ld_chunk_async(const fx4* p, fx4& a){
  asm volatile("global_load_dwordx4 %0, %1, off sc1" : "=&v"(a) : "v"(p) : "memory");
}
__device__ __forceinline__ void wait_vm3(fx4& a, fx4& b, fx4& c){
  asm volatile("s_waitcnt vmcnt(0)" : "+v"(a), "+v"(b), "+v"(c) :: "memory");
}
__device__ __forceinline__ void st_chunk(fx4* p, fx4 v){
  asm volatile("global_store_dwordx4 %0, %1, off sc1" :: "v"(p), "v"(v) : "memory");
}

// ---------------- DPP reductions (VALU pipe, no ds_bpermute latency) ----------------
// dpp_ctrl: ROW_SHL(n)=0x100|n, ROW_SHR(n)=0x110|n, BCAST15=0x142, BCAST31=0x143
template<int CTRL>
__device__ __forceinline__ float dpp_add_f(float v){
  int x = __builtin_amdgcn_update_dpp(0, __builtin_bit_cast(int, v), CTRL, 0xF, 0xF, true);
  return v + __builtin_bit_cast(float, x);
}
template<int CTRL>
__device__ __forceinline__ float dpp_max_f(float v){
  int s = __builtin_bit_cast(int, v);
  int x = __builtin_amdgcn_update_dpp(s, s, CTRL, 0xF, 0xF, false);
  return fmaxf(v, __builtin_bit_cast(float, x));
}
// sum over each 32-lane half; valid at lanes 0 and 32 only
__device__ __forceinline__ float sum32_lo(float v){
  v = dpp_add_f<0x101>(v); v = dpp_add_f<0x102>(v);
  v = dpp_add_f<0x104>(v); v = dpp_add_f<0x108>(v);  // lane 16k = sum of its 16-row
  v += __shfl_xor(v, 16);                            // lane 0/32 = 32-half sums
  return v;
}
// sum over each 32-lane half; valid in ALL lanes
__device__ __forceinline__ float sum32_all(float v){
  v = dpp_add_f<0x111>(v); v = dpp_add_f<0x112>(v);
  v = dpp_add_f<0x114>(v); v = dpp_add_f<0x118>(v);  // lane 16k+15 = row sum
  v = dpp_add_f<0x142>(v);                           // lane 31/63 = half sums
  return __shfl(v, 31, 32);                          // broadcast within each half
}
// full-wave (64) sum, all lanes (via readlane 63)
__device__ __forceinline__ float sum64_all(float v){
  v = dpp_add_f<0x111>(v); v = dpp_add_f<0x112>(v);
  v = dpp_add_f<0x114>(v); v = dpp_add_f<0x118>(v);
  v = dpp_add_f<0x142>(v); v = dpp_add_f<0x143>(v);  // lane 63 = total
  return __builtin_bit_cast(float, __builtin_amdgcn_readlane(__builtin_bit_cast(int, v), 63));
}
// full-wave (64) max, all lanes
__device__ __forceinline__ float max64_all(float v){
  v = dpp_max_f<0x111>(v); v = dpp_max_f<0x112>(v);
  v = dpp_max_f<0x114>(v); v = dpp_max_f<0x118>(v);
  v = dpp_max_f<0x142>(v); v = dpp_max_f<0x143>(v);
  return __builtin_bit_cast(float, __builtin_amdgcn_readlane(__builtin_bit_cast(int, v), 63));
}

// ---------------- pack: Wstack[1025][1280], row 1024 = bias row ----------------
__global__ void pack_kernel(const float* __restrict__ Wxh, const float* __restrict__ bh,
                            const float* __restrict__ Wc,  const float* __restrict__ bc,
                            const float* __restrict__ Wrp, const float* __restrict__ brp,
                            const float* __restrict__ Wwp, const float* __restrict__ bwp,
                            const float* __restrict__ Wrg, const float* __restrict__ brg,
                            const float* __restrict__ Wwg, const float* __restrict__ bwg,
                            float* __restrict__ Wstack)
{
  int n = blockIdx.x*256 + threadIdx.x;
  int k = blockIdx.y;
  if (n >= GSTRIDE) return;
  float v = 0.f;
  if (k < II) {
    if (n < 512)       v = Wxh[k*512 + n];
    else if (n < 1024) v = Wc[k*512 + (n-512)];
    else if (n < 1124) v = Wrp[k*100 + (n-1024)];
    else if (n < 1224) v = Wwp[k*100 + (n-1124)];
    else if (n == 1224) v = Wrg[k];
    else if (n == 1225) v = Wwg[k];
  } else {
    if (n < 512)       v = bh[n];
    else if (n < 1024) v = bc[n-512];
    else if (n < 1124) v = brp[n-1024];
    else if (n < 1224) v = bwp[n-1124];
    else if (n == 1224) v = brg[0];
    else if (n == 1225) v = bwg[0];
  }
  Wstack[k*GSTRIDE + n] = v;
}

// ---------------- GEMM: G = X(32768x1024) @ Wstack(1024x1280) + bias, bf16 out ----------------
__global__ __launch_bounds__(256) void gemm_kernel(const float* __restrict__ X,
                                                   const float* __restrict__ Wstack,
                                                   __hip_bfloat16* __restrict__ G)
{
  __shared__ float As[16][68];
  __shared__ float Bs[16][64];
  const int tid = threadIdx.x;
  const int row0 = blockIdx.y*64, col0 = blockIdx.x*64;
  const int ty = tid>>4, tx = tid&15;
  const int amm = tid>>2, akk = (tid&3)<<2;
  const int bkk = tid>>4, bnn = (tid&15)<<2;
  float acc[4][4] = {{0.f}};
  for (int k0 = 0; k0 < II; k0 += 16) {
    float4 av = *(const float4*)(X + (size_t)(row0+amm)*II + k0 + akk);
    float4 bv = *(const float4*)(Wstack + (size_t)(k0+bkk)*GSTRIDE + col0 + bnn);
    __syncthreads();
    As[akk+0][amm]=av.x; As[akk+1][amm]=av.y; As[akk+2][amm]=av.z; As[akk+3][amm]=av.w;
    *(float4*)&Bs[bkk][bnn] = bv;
    __syncthreads();
#pragma unroll
    for (int kk=0; kk<16; kk++){
      float4 a = *(float4*)&As[kk][ty<<2];
      float4 b = *(float4*)&Bs[kk][tx<<2];
      acc[0][0] += a.x*b.x; acc[0][1] += a.x*b.y; acc[0][2] += a.x*b.z; acc[0][3] += a.x*b.w;
      acc[1][0] += a.y*b.x; acc[1][1] += a.y*b.y; acc[1][2] += a.y*b.z; acc[1][3] += a.y*b.w;
      acc[2][0] += a.z*b.x; acc[2][1] += a.z*b.y; acc[2][2] += a.z*b.z; acc[2][3] += a.z*b.w;
      acc[3][0] += a.w*b.x; acc[3][1] += a.w*b.y; acc[3][2] += a.w*b.z; acc[3][3] += a.w*b.w;
    }
  }
#pragma unroll
  for (int i2=0;i2<4;i2++){
    int r = row0 + (ty<<2) + i2;
#pragma unroll
    for (int j2=0;j2<4;j2++){
      int cidx = col0 + (tx<<2) + j2;
      float v = acc[i2][j2] + Wstack[(size_t)II*GSTRIDE + cidx];
      G[(size_t)r*GSTRIDE + cidx] = __float2bfloat16(v);
    }
  }
}

// ---------------- persistent sequential kernel ----------------
// Round-4 structure (split publish, async group-2 overlap). This round:
// all cross-lane reductions moved from __shfl (ds_bpermute, DS-pipe ~40cy
// dependent latency) to DPP chains (VALU pipe). Transport untouched.
__global__ __launch_bounds__(TSEQ) void seq_kernel(
    const float* __restrict__ Wc,  const float* __restrict__ Wwg,
    const float* __restrict__ Wwp, const float* __restrict__ Wrg,
    const float* __restrict__ Wrp, const float* __restrict__ Wrh,
    const float* __restrict__ Whh,
    const __hip_bfloat16* __restrict__ G,
    float* __restrict__ out,
    fx4* rec4, int N)
{
  const int w = blockIdx.x;
  const int t = threadIdx.x;
  const int j = t >> 5;        // 0..15 local column
  const int l = t & 31;
  const int jg = w*JW + j;     // global h column

  // group-1 staging: row = source WG, [0..15]=h, [16..31]=c, [32..35]=wp (pad to 40)
  __shared__ __align__(16) float raw1[NWG][40];
  // group-2 staging: row = source WG, rp partials [0..100] (pad to 104)
  __shared__ float raw2[NWG][104];
  __shared__ float pubbuf[36];
  __shared__ float pub2[104];
  __shared__ float ht[JW];
  __shared__ float e_ar[104], aw_n[104];
  __shared__ float part6[4][104];
  __shared__ float part2[4][128];
  __shared__ float memW[JW][104];
  __shared__ float Wrp_sl[JW][104];
  __shared__ float Wwp_sl[4][HH];
  __shared__ float scal_s[2];

  // register-resident column slices: Whh[:,jg], Wc_h[:,jg], Wrh[:,jg]
  float whh_r[16], wch_r[16], wrh_r[16];
#pragma unroll
  for (int i=0;i<16;i++){
    int k = i*32 + l;
    whh_r[i] = Whh[(size_t)k*HH + jg];
    wch_r[i] = Wc[(size_t)(II+k)*HH + jg];
    wrh_r[i] = Wrh[(size_t)k*HH + jg];
  }
  for (int idx=t; idx<JW*104; idx+=TSEQ){
    int kl = idx/104, m = idx - kl*104;
    int kgl = II + w*JW + kl;
    float v = 0.f;
    if (m < 100) v = Wrp[(size_t)kgl*100 + m];
    else if (m == 100) v = Wrg[kgl];
    Wrp_sl[kl][m] = v;
    memW[kl][m] = 0.f;
  }
  for (int idx=t; idx<4*HH; idx+=TSEQ){
    int ci = idx>>9, k = idx&511;
    int cg = ci*32 + w;
    float v = 0.f;
    if (cg < 100) v = Wwp[(size_t)(II+k)*100 + cg];
    else if (cg == 100) v = Wwg[II+k];
    Wwp_sl[ci][k] = v;
  }
  if (t < 36) pubbuf[t] = 0.f;
  if (t < 104) pub2[t] = 0.f;
  __syncthreads();

  // ---- step 0: h0 = relu(G_xh[0]), c0 = relu(G_c[0]); wp logits(h_-1=0)=0 ----
  if (t < JW) {
    float hv = fmaxf(0.f, bf2f(G[(size_t)0*GSTRIDE + w*JW + t]));
    float cv = fmaxf(0.f, bf2f(G[(size_t)0*GSTRIDE + 512 + w*JW + t]));
    ht[t] = hv;
    pubbuf[t] = hv;
    pubbuf[16+t] = cv;
    out[(size_t)0*HH + w*JW + t] = hv;
  }
  __syncthreads();
  if (t < 101) {
    float s = 0.f;
#pragma unroll
    for (int kl=0; kl<16; kl++) s += ht[kl]*Wrp_sl[kl][t];
    pub2[t] = s;
  }
  __syncthreads();
  if (t < CHK1) {
    fx4 v; v.x = pubbuf[3*t]; v.y = pubbuf[3*t+1]; v.z = pubbuf[3*t+2];
    v.w = u2f(1u);
    st_chunk(rec4 + (size_t)w*REC + t, v);
  }
  if (t < CHK2) {
    fx4 v; v.x = pub2[3*t]; v.y = pub2[3*t+1]; v.z = pub2[3*t+2];
    v.w = u2f(1u);
    st_chunk(rec4 + (size_t)w*REC + CHK1 + t, v);
  }

  // loop-invariant group-2 chunk assignment: qa=t, qb=t+512, qc=t+1024 (t<64)
  const int wA = t/CHK2,        cjA = t - wA*CHK2;
  const int wB = (t+512)/CHK2,  cjB = (t+512) - wB*CHK2;
  const int wC = (t+1024)/CHK2, cjC = (t+1024) - wC*CHK2;   // valid only t<64
  const int offA = wA*REC + CHK1 + cjA;
  const int offB = wB*REC + CHK1 + cjB;
  const int offC = wC*REC + CHK1 + cjC;

  for (int step=1; step<N; ++step) {
    const unsigned tg = (unsigned)step;
    // (A) prefetch this step's G values into registers
    float g_rp0=0.f, g_rp1=0.f, g_aw0=0.f, g_aw1=0.f, g_h=0.f, g_c=0.f;
    {
      const __hip_bfloat16* Grow = G + (size_t)step*GSTRIDE;
      if (t < 64) {
        g_rp0 = bf2f(Grow[1024+t]);
        int m2 = t+64;
        g_rp1 = bf2f(Grow[m2==100 ? 1224 : 1024+m2]);
      } else if (t < 128) {
        const __hip_bfloat16* Gpr = G + (size_t)(step-1)*GSTRIDE;
        int u = t-64;
        g_aw0 = bf2f(Gpr[1124+u]);
        int m2 = u+64;
        g_aw1 = bf2f(Gpr[m2==100 ? 1225 : 1124+m2]);
      }
      if (l == 0) { g_h = bf2f(Grow[jg]); g_c = bf2f(Grow[512+jg]); }
    }
    const fx4* prev4 = rec4 + (size_t)((step&1)^1)*NWG*REC;
    // (B1) spin group-1 (h/c/wp): t<384 one chunk each
    if (t < NWG*CHK1) {
      int sw = t / CHK1, ci = t - sw*CHK1;
      const fx4* p = prev4 + sw*REC + ci;
      fx4 a;
      ld_chunk1(p, a);
      while (f2u(a.w) != tg) ld_chunk1(p, a);
      float* dst = &raw1[sw][3*ci];
      dst[0] = a.x; dst[1] = a.y; dst[2] = a.z;
    }
    __syncthreads();   // b1a: raw1 complete
    // (B2-issue) async group-2 loads (2/thread, 3 for t<64)
    fx4 a0, a1, a2 = {0.f,0.f,0.f,0.f};
    const fx4 *pA = prev4 + offA, *pB = prev4 + offB, *pC = prev4 + offC;
    ld_chunk_async(pA, a0);
    ld_chunk_async(pB, a1);
    if (t < 64) ld_chunk_async(pC, a2);
    // (C2) register matvecs ph/pc/pw (broadcast LDS reads, DPP reductions)
    float ph=0.f, pc=0.f, pw=0.f;
    {
#pragma unroll
      for (int i=0;i<16;i++){
        int k = i*32 + l;
        float hv  = raw1[k>>4][k&15];
        float cv2 = raw1[k>>4][16+(k&15)];
        ph += whh_r[i]*hv;
        pc += wch_r[i]*hv;
        pw += wrh_r[i]*cv2;
      }
      ph = sum32_lo(ph);   // valid at l==0 (lanes 0,32) — consumed at l==0 only
      pc = sum32_lo(pc);   // idem
      pw = sum32_all(pw);  // consumed by all lanes in (E)
    }
    // (C3) wp partial dots (producer role for next step)
    {
      int ci = t >> 7, li = t & 127;
      float s = 0.f;
#pragma unroll
      for (int ii=0; ii<4; ii++){
        int k = li + 128*ii;
        s += raw1[k>>4][k&15] * Wwp_sl[ci][k];
      }
      part2[ci][li] = s;
    }
    // (B2-wait) drain async loads; retry any stale chunk; de-chunk raw2
    {
      wait_vm3(a0, a1, a2);
      while (f2u(a0.w) != tg) ld_chunk1(pA, a0);
      while (f2u(a1.w) != tg) ld_chunk1(pB, a1);
      if (t < 64) { while (f2u(a2.w) != tg) ld_chunk1(pC, a2); }
      float* d0 = &raw2[wA][3*cjA]; d0[0]=a0.x; d0[1]=a0.y; d0[2]=a0.z;
      float* d1 = &raw2[wB][3*cjB]; d1[0]=a1.x; d1[1]=a1.y; d1[2]=a1.z;
      if (t < 64) { float* d2 = &raw2[wC][3*cjC]; d2[0]=a2.x; d2[1]=a2.y; d2[2]=a2.z; }
    }
    __syncthreads();   // b1b: raw2 complete
    // (C1) merge rp partials across 8-record groups
    if (t < 404) {
      int m = t % 101, q = t / 101;
      const float* b = &raw2[q*8][0] + m;
      float s = ((b[0]+b[104])+(b[208]+b[312])) + ((b[416]+b[520])+(b[624]+b[728]));
      part6[q][m] = s;
    }
    __syncthreads();   // b2: part6/part2 ready
    // (D) wave0: ar softmax; wave1: aw softmax; waves2-5: wp logit reduce
    if (t < 64) {
      int u = t, m2 = u+64;
      float v0 = part6[0][u]+part6[1][u]+part6[2][u]+part6[3][u] + g_rp0;
      float v1 = (m2 <= 100) ? (part6[0][m2]+part6[1][m2]+part6[2][m2]+part6[3][m2] + g_rp1)
                             : -1e30f;
      float vs1 = (m2 < 100) ? v1 : -1e30f;
      float mx = max64_all(fmaxf(v0, vs1));
      float e0 = __expf(v0 - mx), e1 = __expf(vs1 - mx);
      e_ar[u] = e0;
      if (m2 < 104) e_ar[m2] = e1;
      float ssum = sum64_all(e0 + e1);
      float r100 = __shfl(v1, 36);
      if (u == 0) scal_s[0] = (1.f/(1.f+__expf(-r100))) / ssum;
    } else if (t < 128) {
      int u = t-64, m2 = u+64;
      float v0 = raw1[u&31][32+(u>>5)] + g_aw0;
      float v1 = -1e30f;
      if (m2 <= 100) v1 = raw1[m2&31][32+(m2>>5)] + g_aw1;
      float vs1 = (m2 < 100) ? v1 : -1e30f;
      float mx = max64_all(fmaxf(v0, vs1));
      float e0 = __expf(v0 - mx), e1 = __expf(vs1 - mx);
      float ssum = sum64_all(e0 + e1);
      aw_n[u] = e0 / ssum;
      if (m2 < 104) aw_n[m2] = e1 / ssum;
      float r100 = __shfl(v1, 36);
      if (u == 0) scal_s[1] = 1.f/(1.f+__expf(-r100));
    } else if (t < 384) {
      int wv = t >> 6;           // 2..5
      int ci = wv - 2, ln = t & 63;
      float s = part2[ci][ln] + part2[ci][ln+64];
      s = sum64_all(s);
      if (ln == 0 && (ci*32 + w) < 101) pubbuf[32+ci] = s;
    }
    __syncthreads();   // b3: e_ar/aw_n/scal/pubbuf.wp ready
    // (E) memW update fused with rW accumulation; h/c finalize
    {
      float gws = scal_s[1], gos = scal_s[0];
      float rwp = 0.f;
#pragma unroll
      for (int q=0; q<4; q++){
        int m = l + 32*q;
        if (m < 100) {
          float a2 = aw_n[m];
          float mv = memW[j][m];
          mv = (1.f - a2)*mv + gws*a2*pw;
          memW[j][m] = mv;
          rwp += e_ar[m]*mv;
        }
      }
      rwp = sum32_lo(rwp);   // consumed at l==0 only
      float hv = fmaxf(0.f, g_h + ph + gos*rwp);
      if (l == 0) {
        float cv = fmaxf(0.f, g_c + pc);
        ht[j] = hv;
        pubbuf[j] = hv;
        pubbuf[16+j] = cv;
        out[(size_t)step*HH + jg] = hv;
      }
    }
    if (step + 1 < N) {
      __syncthreads();   // b4: ht / pubbuf h,c ready (wp set in D)
      // (G1) fire group-1 IMMEDIATELY (before F) — unblocks consumers early
      fx4* cur4 = rec4 + (size_t)((step&1)*NWG + w)*REC;
      if (t < CHK1) {
        fx4 v; v.x = pubbuf[3*t]; v.y = pubbuf[3*t+1]; v.z = pubbuf[3*t+2];
        v.w = u2f((unsigned)(step+1));
        st_chunk(cur4 + t, v);
      }
      // (F) rp partials for next step (concurrent with G1 on other threads)
      if (t < 101) {
        float s = 0.f;
#pragma unroll
        for (int kl=0; kl<16; kl++) s += ht[kl]*Wrp_sl[kl][t];
        pub2[t] = s;
      }
      __syncthreads();   // b5: pub2 complete
      // (G2) fire group-2
      if (t < CHK2) {
        fx4 v; v.x = pub2[3*t]; v.y = pub2[3*t+1]; v.z = pub2[3*t+2];
        v.w = u2f((unsigned)(step+1));
        st_chunk(cur4 + CHK1 + t, v);
      }
    }
  }
}

extern "C" void kernel_launch(void* const* d_in, const int* in_sizes, int n_in,
                              void* d_out, int out_size, void* d_ws, size_t ws_size,
                              hipStream_t stream) {
  const float* X   = (const float*)d_in[0];
  const float* Wc  = (const float*)d_in[1];
  const float* bc  = (const float*)d_in[2];
  const float* Wwg = (const float*)d_in[3];
  const float* bwg = (const float*)d_in[4];
  const float* Wwp = (const float*)d_in[5];
  const float* bwp = (const float*)d_in[6];
  const float* Wrg = (const float*)d_in[7];
  const float* brg = (const float*)d_in[8];
  const float* Wrp = (const float*)d_in[9];
  const float* brp = (const float*)d_in[10];
  const float* Wxh = (const float*)d_in[11];
  const float* Wrh = (const float*)d_in[12];
  const float* Whh = (const float*)d_in[13];
  const float* bh  = (const float*)d_in[14];

  const int N = in_sizes[0] / II;   // 32768

  char* ws = (char*)d_ws;
  fx4* rec4 = (fx4*)(ws + OFF_REC);
  float* Wstack = (float*)(ws + OFF_WSTACK);
  __hip_bfloat16* G = (__hip_bfloat16*)(ws + OFF_G);
  float* out = (float*)d_out;

  pack_kernel<<<dim3(GSTRIDE/256, II+1), 256, 0, stream>>>(
      Wxh, bh, Wc, bc, Wrp, brp, Wwp, bwp, Wrg, brg, Wwg, bwg, Wstack);

  gemm_kernel<<<dim3(GSTRIDE/64, N/64), 256, 0, stream>>>(X, Wstack, G);

  seq_kernel<<<NWG, TSEQ, 0, stream>>>(
      Wc, Wwg, Wwp, Wrg, Wrp, Wrh, Whh, G, out,
      rec4, N);
}